// Round 1
// baseline (2334.402 us; speedup 1.0000x reference)
//
#include <hip/hip_runtime.h>

// TangentSpaceLoss: loss = (1/B^2) sum_ij softmax_j(E E^T)_ij * ||v_i - v_j||^2
// B=8192 cells, G=512 genes, D=64 latent.
//
// Sparse-softmax algorithm: sim_ii = ||e_i||^2 ~ 64 dominates row softmax;
// only pairs with s_ij > m_i - 32 matter (worst-case neglected mass 2.7e-11
// << 5.4e-10 threshold). Since m_i >= s_ii = ne_i, selecting
// s_ij > min(ne_i, ne_j) - 32 is a safe superset. Expected ~3e5 pairs of 67M.
//
// K1 prep:    n_i = ||v_i||^2, ne_i = ||e_i||^2, bf16 copies of V and E
// K2 select:  bf16 MFMA scan of E E^T (upper triangle), emit passing (i,j)
// K3 rowmax:  fp32 s for each pair -> atomic max m_i (and m_j)
// K4 accum:   fp32 s, bf16-in/fp32-acc g -> Z_i += w, num_i += w*wd (both sides)
// K5 final:   out = sum_i num_i/Z_i / B^2  (fp64 accumulate)

#define B_CELLS 8192
#define G_GENES 512
#define D_LAT   64
#define SEL_T   32.0f

typedef __bf16 bf16x8 __attribute__((ext_vector_type(8)));
typedef float  f32x4  __attribute__((ext_vector_type(4)));

__device__ __forceinline__ unsigned encf(float f) {
    unsigned u = __float_as_uint(f);
    return (f >= 0.f) ? (u | 0x80000000u) : ~u;
}
__device__ __forceinline__ float decf(unsigned e) {
    return (e & 0x80000000u) ? __uint_as_float(e & 0x7FFFFFFFu)
                             : __uint_as_float(~e);
}

// ---------------- K1: norms + bf16 casts --------------------------------
__global__ __launch_bounds__(256) void k_prep(
    const float* __restrict__ V, const float* __restrict__ E,
    float* __restrict__ n, float* __restrict__ ne,
    __bf16* __restrict__ Ebf, __bf16* __restrict__ Vbf) {
    int row  = (blockIdx.x << 2) + (threadIdx.x >> 6);   // 2048 blocks * 4 waves
    int lane = threadIdx.x & 63;
    const float* vr = V + (size_t)row * G_GENES;
    __bf16* vb = Vbf + (size_t)row * G_GENES;
    float sn = 0.f;
#pragma unroll
    for (int k = 0; k < 8; ++k) {
        float x = vr[k * 64 + lane];
        vb[k * 64 + lane] = (__bf16)x;
        sn += x * x;
    }
    float el = E[row * D_LAT + lane];
    Ebf[row * D_LAT + lane] = (__bf16)el;
    float se = el * el;
#pragma unroll
    for (int m = 1; m < 64; m <<= 1) {
        sn += __shfl_xor(sn, m, 64);
        se += __shfl_xor(se, m, 64);
    }
    if (lane == 0) { n[row] = sn; ne[row] = se; }
}

// ---------------- K2: bf16 MFMA scan + pair selection -------------------
// Block: 256 thr = 4 waves, tile 64i x 64j. Upper triangle tiles only.
// LDS stride 72 bf16 (=36 dwords) -> 2-way bank aliasing (free) on b128 reads.
__global__ __launch_bounds__(256) void k_select(
    const __bf16* __restrict__ Ebf, const float* __restrict__ ne,
    unsigned* __restrict__ cnt, unsigned* __restrict__ pairs, unsigned cap) {
    unsigned blk = blockIdx.x;
    int bx = blk & 127, by = blk >> 7;
    if (bx > by) return;              // i-tile <= j-tile (canonical i<=j)
    int i0 = bx << 6, j0 = by << 6;
    __shared__ __align__(16) __bf16 sEi[64 * 72];
    __shared__ __align__(16) __bf16 sEj[64 * 72];
    __shared__ float sNeI[64], sNeJ[64];
    int tid = threadIdx.x;
    const unsigned* gEi = (const unsigned*)(Ebf + (size_t)i0 * D_LAT);
    const unsigned* gEj = (const unsigned*)(Ebf + (size_t)j0 * D_LAT);
    unsigned* lEi = (unsigned*)sEi;
    unsigned* lEj = (unsigned*)sEj;
    for (int t = tid; t < 64 * 32; t += 256) {      // 64 rows * 32 dwords
        int r = t >> 5, c = t & 31;
        lEi[r * 36 + c] = gEi[r * 32 + c];
        lEj[r * 36 + c] = gEj[r * 32 + c];
    }
    if (tid < 64)           sNeI[tid]      = ne[i0 + tid];
    else if (tid < 128)     sNeJ[tid - 64] = ne[j0 + tid - 64];
    __syncthreads();

    int wave = tid >> 6, lane = tid & 63;
    int m = lane & 15, quad = lane >> 4;
    int ibase = wave << 4;                          // wave owns 16 i-rows
    const bf16x8 a0 = *(const bf16x8*)(sEi + (ibase + m) * 72 + quad * 8);
    const bf16x8 a1 = *(const bf16x8*)(sEi + (ibase + m) * 72 + 32 + quad * 8);
    bool diag = (bx == by);
#pragma unroll
    for (int jc = 0; jc < 4; ++jc) {
        bf16x8 b0 = *(const bf16x8*)(sEj + (jc * 16 + m) * 72 + quad * 8);
        bf16x8 b1 = *(const bf16x8*)(sEj + (jc * 16 + m) * 72 + 32 + quad * 8);
        f32x4 acc = {0.f, 0.f, 0.f, 0.f};
        acc = __builtin_amdgcn_mfma_f32_16x16x32_bf16(a0, b0, acc, 0, 0, 0);
        acc = __builtin_amdgcn_mfma_f32_16x16x32_bf16(a1, b1, acc, 0, 0, 0);
        int jg = j0 + jc * 16 + m;                  // C col = lane&15
        float nej = sNeJ[jc * 16 + m];
#pragma unroll
        for (int r = 0; r < 4; ++r) {
            int il = ibase + quad * 4 + r;          // C row = quad*4+reg
            int ig = i0 + il;
            if (diag && ig > jg) continue;          // keep i<=j only
            float nei = sNeI[il];
            float thr = (ig == jg) ? nei : fminf(nei, nej);
            float s = acc[r];
            if (s > thr - SEL_T) {
                unsigned idx = atomicAdd(cnt, 1u);
                if (idx < cap)
                    pairs[idx] = ((unsigned)ig << 13) | (unsigned)jg;
            }
        }
    }
}

// ---------------- K3: per-pair fp32 s -> row max ------------------------
__global__ __launch_bounds__(256) void k_rowmax(
    const float* __restrict__ E, const unsigned* __restrict__ cnt,
    const unsigned* __restrict__ pairs, unsigned cap,
    unsigned* __restrict__ menc) {
    unsigned np = *cnt; if (np > cap) np = cap;
    unsigned nw  = (gridDim.x * blockDim.x) >> 6;
    unsigned wid = (blockIdx.x * blockDim.x + threadIdx.x) >> 6;
    int lane = threadIdx.x & 63;
    for (unsigned p = wid; p < np; p += nw) {
        unsigned u = pairs[p];
        int i = u >> 13, j = u & 8191;
        float s = E[i * D_LAT + lane] * E[j * D_LAT + lane];
#pragma unroll
        for (int msk = 1; msk < 64; msk <<= 1) s += __shfl_xor(s, msk, 64);
        if (lane == 0) {
            unsigned es = encf(s);
            atomicMax(menc + i, es);
            if (j != i) atomicMax(menc + j, es);
        }
    }
}

// ---------------- K4: per-pair Z / num accumulation ---------------------
__global__ __launch_bounds__(256) void k_accum(
    const float* __restrict__ E, const __bf16* __restrict__ Vbf,
    const float* __restrict__ n, const unsigned* __restrict__ cnt,
    const unsigned* __restrict__ pairs, unsigned cap,
    const unsigned* __restrict__ menc,
    float* __restrict__ Z, float* __restrict__ num) {
    unsigned np = *cnt; if (np > cap) np = cap;
    unsigned nw  = (gridDim.x * blockDim.x) >> 6;
    unsigned wid = (blockIdx.x * blockDim.x + threadIdx.x) >> 6;
    int lane = threadIdx.x & 63;
    for (unsigned p = wid; p < np; p += nw) {
        unsigned u = pairs[p];
        int i = u >> 13, j = u & 8191;
        float s = E[i * D_LAT + lane] * E[j * D_LAT + lane];
        float g = 0.f;
        const __bf16* vi = Vbf + (size_t)i * G_GENES;
        const __bf16* vj = Vbf + (size_t)j * G_GENES;
#pragma unroll
        for (int k = 0; k < 8; ++k)
            g += (float)vi[k * 64 + lane] * (float)vj[k * 64 + lane];
#pragma unroll
        for (int msk = 1; msk < 64; msk <<= 1) {
            s += __shfl_xor(s, msk, 64);
            g += __shfl_xor(g, msk, 64);
        }
        if (lane == 0) {
            float mi = decf(menc[i]);
            float wi = __expf(s - mi);
            if (i == j) {
                atomicAdd(Z + i, wi);               // wd_ii = 0 exactly
            } else {
                float wd = n[i] + n[j] - 2.f * g;
                atomicAdd(Z + i, wi);
                atomicAdd(num + i, wi * wd);
                float mj = decf(menc[j]);
                float wj = __expf(s - mj);
                atomicAdd(Z + j, wj);
                atomicAdd(num + j, wj * wd);
            }
        }
    }
}

// ---------------- K5: final reduction -----------------------------------
__global__ __launch_bounds__(256) void k_final(
    const float* __restrict__ Z, const float* __restrict__ num,
    float* __restrict__ out) {
    __shared__ double sd[256];
    double acc = 0.0;
    for (int i = threadIdx.x; i < B_CELLS; i += 256) {
        float z = Z[i];
        if (z > 0.f) acc += (double)num[i] / (double)z;
    }
    sd[threadIdx.x] = acc;
    __syncthreads();
    for (int s = 128; s > 0; s >>= 1) {
        if (threadIdx.x < s) sd[threadIdx.x] += sd[threadIdx.x + s];
        __syncthreads();
    }
    if (threadIdx.x == 0)
        out[0] = (float)(sd[0] / ((double)B_CELLS * (double)B_CELLS));
}

// ---------------- host launcher -----------------------------------------
extern "C" void kernel_launch(void* const* d_in, const int* in_sizes, int n_in,
                              void* d_out, int out_size, void* d_ws, size_t ws_size,
                              hipStream_t stream) {
    const float* V = (const float*)d_in[0];   // [8192, 512] f32
    const float* E = (const float*)d_in[1];   // [8192, 64]  f32
    float* out = (float*)d_out;
    char* ws = (char*)d_ws;

    // ws layout (bytes)
    float*    n_    = (float*)(ws + 0);              // 32 KB
    float*    ne    = (float*)(ws + 32768);          // 32 KB
    unsigned* menc  = (unsigned*)(ws + 65536);       // 32 KB
    float*    Z     = (float*)(ws + 98304);          // 32 KB
    float*    num   = (float*)(ws + 131072);         // 32 KB
    unsigned* cnt   = (unsigned*)(ws + 163840);      // 64 B
    __bf16*   Ebf   = (__bf16*)(ws + 163904);        // 1 MB
    __bf16*   Vbf   = (__bf16*)(ws + 1212480);       // 8 MB
    unsigned* pairs = (unsigned*)(ws + 9601088);
    const size_t fixed = 9601088;
    unsigned cap = 0;
    if (ws_size > fixed + 64) {
        size_t c = (ws_size - fixed - 64) / sizeof(unsigned);
        cap = (c > 4194304u) ? 4194304u : (unsigned)c;   // up to 4M pairs
    }

    // zero menc, Z, num, cnt (65536 .. 163904)
    hipMemsetAsync((void*)(ws + 65536), 0, 98368, stream);

    k_prep  <<<2048, 256, 0, stream>>>(V, E, n_, ne, Ebf, Vbf);
    k_select<<<16384, 256, 0, stream>>>(Ebf, ne, cnt, pairs, cap);
    k_rowmax<<<1024, 256, 0, stream>>>(E, cnt, pairs, cap, menc);
    k_accum <<<4096, 256, 0, stream>>>(E, Vbf, n_, cnt, pairs, cap, menc, Z, num);
    k_final <<<1, 256, 0, stream>>>(Z, num, out);
}

// Round 2
// 336.379 us; speedup vs baseline: 6.9398x; 6.9398x over previous
//
#include <hip/hip_runtime.h>

// TangentSpaceLoss: loss = (1/B^2) sum_ij softmax_j(E E^T)_ij * ||v_i - v_j||^2
// B=8192 cells, G=512 genes, D=64 latent.
//
// Sparse-softmax algorithm: sim_ii = ||e_i||^2 ~ 64 dominates row softmax;
// only pairs with s_ij > m_i - 32 matter. Since m_i >= s_ii = ne_i, selecting
// s_ij > min(ne_i, ne_j) - 32 is a safe superset (~2.2M pairs of 67M, measured R1).
// Softmax is shift-invariant, so we shift by ne_i (no row-max pass needed);
// worst exponent s - ne_i <= sqrt(ne_i*ne_j) - ne_i ~ 35 -> fp32-safe.
//
// K1 prep:    n_i = ||v_i||^2, ne_i = ||e_i||^2, bf16 copies of V and E
// K2 select:  bf16 MFMA scan of E E^T (upper triangle), LDS-aggregated pair
//             emission -> ONE global atomic per block (R1: per-candidate
//             atomics on one address serialized 1905us at ~2cyc/atomic)
// K3 accum:   fp32 s, bf16-in/fp32-acc g -> Z_i += w, num_i += w*wd (both sides)
// K4 final:   out = sum_i num_i/Z_i / B^2  (fp64 accumulate)

#define B_CELLS 8192
#define G_GENES 512
#define D_LAT   64
#define SEL_T   32.0f

typedef __bf16 bf16x8 __attribute__((ext_vector_type(8)));
typedef float  f32x4  __attribute__((ext_vector_type(4)));

// ---------------- K1: norms + bf16 casts --------------------------------
__global__ __launch_bounds__(256) void k_prep(
    const float* __restrict__ V, const float* __restrict__ E,
    float* __restrict__ n, float* __restrict__ ne,
    __bf16* __restrict__ Ebf, __bf16* __restrict__ Vbf) {
    int row  = (blockIdx.x << 2) + (threadIdx.x >> 6);   // 2048 blocks * 4 waves
    int lane = threadIdx.x & 63;
    const float* vr = V + (size_t)row * G_GENES;
    __bf16* vb = Vbf + (size_t)row * G_GENES;
    float sn = 0.f;
#pragma unroll
    for (int k = 0; k < 8; ++k) {
        float x = vr[k * 64 + lane];
        vb[k * 64 + lane] = (__bf16)x;
        sn += x * x;
    }
    float el = E[row * D_LAT + lane];
    Ebf[row * D_LAT + lane] = (__bf16)el;
    float se = el * el;
#pragma unroll
    for (int m = 1; m < 64; m <<= 1) {
        sn += __shfl_xor(sn, m, 64);
        se += __shfl_xor(se, m, 64);
    }
    if (lane == 0) { n[row] = sn; ne[row] = se; }
}

// ---------------- K2: bf16 MFMA scan + pair selection -------------------
// Block: 256 thr = 4 waves, tile 64i x 64j. Upper triangle tiles only.
// LDS stride 72 bf16 (=36 dwords = 9 uint4) -> 2-way bank aliasing (free).
// Pair emission: LDS list + one global atomicAdd per block.
__global__ __launch_bounds__(256) void k_select(
    const __bf16* __restrict__ Ebf, const float* __restrict__ ne,
    unsigned* __restrict__ cnt, unsigned* __restrict__ pairs, unsigned cap) {
    unsigned blk = blockIdx.x;
    int bx = blk & 127, by = blk >> 7;
    if (bx > by) return;              // i-tile <= j-tile (canonical i<=j)
    int i0 = bx << 6, j0 = by << 6;
    __shared__ __align__(16) __bf16 sEi[64 * 72];
    __shared__ __align__(16) __bf16 sEj[64 * 72];
    __shared__ float sNeI[64], sNeJ[64];
    __shared__ unsigned lbuf[4096];   // 64x64 tile: <=4096 candidates, exact bound
    __shared__ unsigned lcnt, lbase;
    int tid = threadIdx.x;
    if (tid == 0) lcnt = 0;
    const uint4* gEi = (const uint4*)(Ebf + (size_t)i0 * D_LAT);
    const uint4* gEj = (const uint4*)(Ebf + (size_t)j0 * D_LAT);
    uint4* lEi = (uint4*)sEi;
    uint4* lEj = (uint4*)sEj;
    for (int t = tid; t < 64 * 8; t += 256) {       // 64 rows * 8 uint4
        int r = t >> 3, c = t & 7;
        lEi[r * 9 + c] = gEi[r * 8 + c];
        lEj[r * 9 + c] = gEj[r * 8 + c];
    }
    if (tid < 64)           sNeI[tid]      = ne[i0 + tid];
    else if (tid < 128)     sNeJ[tid - 64] = ne[j0 + tid - 64];
    __syncthreads();

    int wave = tid >> 6, lane = tid & 63;
    int m = lane & 15, quad = lane >> 4;
    int ibase = wave << 4;                          // wave owns 16 i-rows
    const bf16x8 a0 = *(const bf16x8*)(sEi + (ibase + m) * 72 + quad * 8);
    const bf16x8 a1 = *(const bf16x8*)(sEi + (ibase + m) * 72 + 32 + quad * 8);
    bool diag = (bx == by);
#pragma unroll
    for (int jc = 0; jc < 4; ++jc) {
        bf16x8 b0 = *(const bf16x8*)(sEj + (jc * 16 + m) * 72 + quad * 8);
        bf16x8 b1 = *(const bf16x8*)(sEj + (jc * 16 + m) * 72 + 32 + quad * 8);
        f32x4 acc = {0.f, 0.f, 0.f, 0.f};
        acc = __builtin_amdgcn_mfma_f32_16x16x32_bf16(a0, b0, acc, 0, 0, 0);
        acc = __builtin_amdgcn_mfma_f32_16x16x32_bf16(a1, b1, acc, 0, 0, 0);
        int jg = j0 + jc * 16 + m;                  // C col = lane&15
        float nej = sNeJ[jc * 16 + m];
#pragma unroll
        for (int r = 0; r < 4; ++r) {
            int il = ibase + quad * 4 + r;          // C row = quad*4+reg
            int ig = i0 + il;
            if (diag && ig > jg) continue;          // keep i<=j only
            float nei = sNeI[il];
            float thr = (ig == jg) ? nei : fminf(nei, nej);
            if (acc[r] > thr - SEL_T) {
                unsigned idx = atomicAdd(&lcnt, 1u);   // LDS atomic
                lbuf[idx] = ((unsigned)ig << 13) | (unsigned)jg;
            }
        }
    }
    __syncthreads();
    unsigned nc = lcnt;
    if (tid == 0 && nc) lbase = atomicAdd(cnt, nc);    // ONE global atomic/block
    __syncthreads();
    unsigned base = lbase;
    for (unsigned t = tid; t < nc; t += 256) {
        unsigned d = base + t;
        if (d < cap) pairs[d] = lbuf[t];
    }
}

// ---------------- K3: per-pair Z / num accumulation ---------------------
// One wave per pair. s in fp32 from E; g from bf16 V via uint4 loads +
// bit-shift unpack (bf16 = top half of f32). Softmax shift = ne (diagonal).
__device__ __forceinline__ float bfdot4(uint4 a, uint4 b, float g) {
    const unsigned* pa = (const unsigned*)&a;
    const unsigned* pb = (const unsigned*)&b;
#pragma unroll
    for (int k = 0; k < 4; ++k) {
        float alo = __uint_as_float(pa[k] << 16);
        float blo = __uint_as_float(pb[k] << 16);
        float ahi = __uint_as_float(pa[k] & 0xFFFF0000u);
        float bhi = __uint_as_float(pb[k] & 0xFFFF0000u);
        g = fmaf(alo, blo, g);
        g = fmaf(ahi, bhi, g);
    }
    return g;
}

__global__ __launch_bounds__(256) void k_accum(
    const float* __restrict__ E, const __bf16* __restrict__ Vbf,
    const float* __restrict__ n, const float* __restrict__ ne,
    const unsigned* __restrict__ cnt, const unsigned* __restrict__ pairs,
    unsigned cap, float* __restrict__ Z, float* __restrict__ num) {
    unsigned np = *cnt; if (np > cap) np = cap;
    unsigned nw  = (gridDim.x * blockDim.x) >> 6;
    unsigned wid = (blockIdx.x * blockDim.x + threadIdx.x) >> 6;
    int lane = threadIdx.x & 63;
    for (unsigned p = wid; p < np; p += nw) {
        unsigned u = pairs[p];
        int i = u >> 13, j = u & 8191;
        float s = E[i * D_LAT + lane] * E[j * D_LAT + lane];
        const uint4* vi = (const uint4*)(Vbf + (size_t)i * G_GENES);
        const uint4* vj = (const uint4*)(Vbf + (size_t)j * G_GENES);
        float g = bfdot4(vi[lane], vj[lane], 0.f);
#pragma unroll
        for (int msk = 1; msk < 64; msk <<= 1) {
            s += __shfl_xor(s, msk, 64);
            g += __shfl_xor(g, msk, 64);
        }
        if (lane == 0) {
            float wi = __expf(s - ne[i]);
            if (i == j) {
                atomicAdd(Z + i, wi);               // wd_ii = 0 exactly
            } else {
                float wd = n[i] + n[j] - 2.f * g;
                float wj = __expf(s - ne[j]);
                atomicAdd(Z + i, wi);
                atomicAdd(num + i, wi * wd);
                atomicAdd(Z + j, wj);
                atomicAdd(num + j, wj * wd);
            }
        }
    }
}

// ---------------- K4: final reduction -----------------------------------
__global__ __launch_bounds__(256) void k_final(
    const float* __restrict__ Z, const float* __restrict__ num,
    float* __restrict__ out) {
    __shared__ double sd[256];
    double acc = 0.0;
    for (int i = threadIdx.x; i < B_CELLS; i += 256) {
        float z = Z[i];
        if (z > 0.f) acc += (double)num[i] / (double)z;
    }
    sd[threadIdx.x] = acc;
    __syncthreads();
    for (int s = 128; s > 0; s >>= 1) {
        if (threadIdx.x < s) sd[threadIdx.x] += sd[threadIdx.x + s];
        __syncthreads();
    }
    if (threadIdx.x == 0)
        out[0] = (float)(sd[0] / ((double)B_CELLS * (double)B_CELLS));
}

// ---------------- host launcher -----------------------------------------
extern "C" void kernel_launch(void* const* d_in, const int* in_sizes, int n_in,
                              void* d_out, int out_size, void* d_ws, size_t ws_size,
                              hipStream_t stream) {
    const float* V = (const float*)d_in[0];   // [8192, 512] f32
    const float* E = (const float*)d_in[1];   // [8192, 64]  f32
    float* out = (float*)d_out;
    char* ws = (char*)d_ws;

    // ws layout (bytes)
    float*    n_    = (float*)(ws + 0);              // 32 KB
    float*    ne    = (float*)(ws + 32768);          // 32 KB
    float*    Z     = (float*)(ws + 98304);          // 32 KB
    float*    num   = (float*)(ws + 131072);         // 32 KB
    unsigned* cnt   = (unsigned*)(ws + 163840);      // 64 B
    __bf16*   Ebf   = (__bf16*)(ws + 163904);        // 1 MB
    __bf16*   Vbf   = (__bf16*)(ws + 1212480);       // 8 MB
    unsigned* pairs = (unsigned*)(ws + 9601088);
    const size_t fixed = 9601088;
    unsigned cap = 0;
    if (ws_size > fixed + 64) {
        size_t c = (ws_size - fixed - 64) / sizeof(unsigned);
        cap = (c > 8388608u) ? 8388608u : (unsigned)c;   // up to 8M pairs
    }

    // zero Z, num, cnt (98304 .. 163904)
    hipMemsetAsync((void*)(ws + 98304), 0, 65600, stream);

    k_prep  <<<2048, 256, 0, stream>>>(V, E, n_, ne, Ebf, Vbf);
    k_select<<<16384, 256, 0, stream>>>(Ebf, ne, cnt, pairs, cap);
    k_accum <<<8192, 256, 0, stream>>>(E, Vbf, n_, ne, cnt, pairs, cap, Z, num);
    k_final <<<1, 256, 0, stream>>>(Z, num, out);
}

// Round 3
// 301.942 us; speedup vs baseline: 7.7313x; 1.1141x over previous
//
#include <hip/hip_runtime.h>

// TangentSpaceLoss: loss = (1/B^2) sum_ij softmax_j(E E^T)_ij * ||v_i - v_j||^2
// B=8192, G=512, D=64.
//
// R2 post-mortem: pair-list gather = 2560 B/pair * 2.2M pairs = 5.6 GB from L2
// = 34.8 TB/s = L2 ceiling -> L2-BW-bound. Fix: tile-wise MFMA processing, no
// pair list. Each 64x64 upper-triangle tile stages V rows ONCE (128 KB/tile,
// 1.35 GB total vs 5.6 GB) and computes:
//   S tile: fp16 MFMA with residual correction (E=h+r; s=hh'+hr'+rh', err~1e-4)
//   G tile: fp16 MFMA, K=512 (g err ~0.008 on wd~1e3 -> 1.6e-5 rel)
// Selection: s > min(ne_i,ne_j)-32 (proven-safe superset; neglected mass
// 2.7e-11 << 5.4e-10 threshold). Softmax shift = ne_i (shift-invariance);
// diagonal w_ii=1, wd_ii=0 -> Z pre-init to 1, diag cells skipped.
// Epilogue: shuffle-reduce partials, ~256 spread global atomics per block
// (LDS atomics would serialize ~200us - avoided).

#define B_CELLS 8192
#define G_GENES 512
#define D_LAT   64
#define SEL_T   32.0f

typedef _Float16 half8 __attribute__((ext_vector_type(8)));
typedef float    f32x4 __attribute__((ext_vector_type(4)));

// ---------------- K1: norms + fp16 (h + residual) casts -----------------
__global__ __launch_bounds__(256) void k_prep(
    const float* __restrict__ V, const float* __restrict__ E,
    float* __restrict__ n, float* __restrict__ ne, float* __restrict__ Z,
    _Float16* __restrict__ Eh, _Float16* __restrict__ Er,
    _Float16* __restrict__ Vh) {
    int row  = (blockIdx.x << 2) + (threadIdx.x >> 6);   // 2048 blocks * 4 waves
    int lane = threadIdx.x & 63;
    const float* vr = V + (size_t)row * G_GENES;
    _Float16* vh = Vh + (size_t)row * G_GENES;
    float sn = 0.f;
#pragma unroll
    for (int k = 0; k < 8; ++k) {
        float x = vr[k * 64 + lane];
        vh[k * 64 + lane] = (_Float16)x;
        sn += x * x;
    }
    float el = E[row * D_LAT + lane];
    _Float16 hx = (_Float16)el;
    Eh[row * D_LAT + lane] = hx;
    Er[row * D_LAT + lane] = (_Float16)(el - (float)hx);
    float se = el * el;
#pragma unroll
    for (int m = 1; m < 64; m <<= 1) {
        sn += __shfl_xor(sn, m, 64);
        se += __shfl_xor(se, m, 64);
    }
    if (lane == 0) { n[row] = sn; ne[row] = se; Z[row] = 1.0f; }
}

// ---------------- K2: fused tile kernel ---------------------------------
// 256 thr = 4 waves per 64x64 upper tile. Wave w owns i-rows [16w,16w+16).
// LDS stride 72 halfs (=36 dwords): fragment b128 reads land 8-deep/bank
// (the wave64 minimum).
__global__ __launch_bounds__(256) void k_mega(
    const _Float16* __restrict__ Eh, const _Float16* __restrict__ Er,
    const _Float16* __restrict__ Vh,
    const float* __restrict__ ne, const float* __restrict__ nrm,
    float* __restrict__ Z, float* __restrict__ num) {
    unsigned blk = blockIdx.x;
    int bx = blk & 127, by = blk >> 7;
    if (bx > by) return;                       // canonical i-tile <= j-tile
    int i0 = bx << 6, j0 = by << 6;
    bool diag = (bx == by);

    __shared__ __align__(16) _Float16 sAh[64 * 72];
    __shared__ __align__(16) _Float16 sAr[64 * 72];
    __shared__ __align__(16) _Float16 sBh[64 * 72];
    __shared__ __align__(16) _Float16 sBr[64 * 72];
    __shared__ __align__(16) _Float16 sVa[2][64 * 72];
    __shared__ __align__(16) _Float16 sVb[2][64 * 72];
    __shared__ float sNeI[64], sNeJ[64], sNI[64], sNJ[64];
    __shared__ float sJred[4][64][2];

    int tid = threadIdx.x;
    // stage E h/r tiles (64 rows x 8 uint4 each)
    {
        const uint4* gAh = (const uint4*)(Eh + (size_t)i0 * D_LAT);
        const uint4* gAr = (const uint4*)(Er + (size_t)i0 * D_LAT);
        const uint4* gBh = (const uint4*)(Eh + (size_t)j0 * D_LAT);
        const uint4* gBr = (const uint4*)(Er + (size_t)j0 * D_LAT);
        uint4* lAh = (uint4*)sAh; uint4* lAr = (uint4*)sAr;
        uint4* lBh = (uint4*)sBh; uint4* lBr = (uint4*)sBr;
        for (int t = tid; t < 512; t += 256) {
            int r = t >> 3, c = t & 7;
            lAh[r * 9 + c] = gAh[r * 8 + c];
            lAr[r * 9 + c] = gAr[r * 8 + c];
            lBh[r * 9 + c] = gBh[r * 8 + c];
            lBr[r * 9 + c] = gBr[r * 8 + c];
        }
        if (tid < 64)      { sNeI[tid] = ne[i0 + tid];  sNI[tid] = nrm[i0 + tid]; }
        else if (tid < 128){ sNeJ[tid-64] = ne[j0 + tid-64]; sNJ[tid-64] = nrm[j0 + tid-64]; }
    }
    __syncthreads();

    int wave = tid >> 6, lane = tid & 63;
    int m = lane & 15, quad = lane >> 4;
    int ibase = wave << 4;

    // stage V chunk 0 (issued before S compute for overlap)
    const uint4* gVa = (const uint4*)(Vh + (size_t)i0 * G_GENES);
    const uint4* gVb = (const uint4*)(Vh + (size_t)j0 * G_GENES);
    {
        uint4* la = (uint4*)(sVa[0]); uint4* lb = (uint4*)(sVb[0]);
        for (int t = tid; t < 512; t += 256) {
            int r = t >> 3, c = t & 7;
            la[r * 9 + c] = gVa[(size_t)r * 64 + c];
            lb[r * 9 + c] = gVb[(size_t)r * 64 + c];
        }
    }

    // ---- S tiles: hh' + hr' + rh' (fp16 + residual) ----
    f32x4 sacc[4];
    {
        const half8 ah0 = *(const half8*)(sAh + (ibase + m) * 72 + quad * 8);
        const half8 ah1 = *(const half8*)(sAh + (ibase + m) * 72 + 32 + quad * 8);
        const half8 ar0 = *(const half8*)(sAr + (ibase + m) * 72 + quad * 8);
        const half8 ar1 = *(const half8*)(sAr + (ibase + m) * 72 + 32 + quad * 8);
#pragma unroll
        for (int jc = 0; jc < 4; ++jc) {
            const half8 bh0 = *(const half8*)(sBh + (jc * 16 + m) * 72 + quad * 8);
            const half8 bh1 = *(const half8*)(sBh + (jc * 16 + m) * 72 + 32 + quad * 8);
            const half8 br0 = *(const half8*)(sBr + (jc * 16 + m) * 72 + quad * 8);
            const half8 br1 = *(const half8*)(sBr + (jc * 16 + m) * 72 + 32 + quad * 8);
            f32x4 acc = {0.f, 0.f, 0.f, 0.f};
            acc = __builtin_amdgcn_mfma_f32_16x16x32_f16(ah0, bh0, acc, 0, 0, 0);
            acc = __builtin_amdgcn_mfma_f32_16x16x32_f16(ah1, bh1, acc, 0, 0, 0);
            acc = __builtin_amdgcn_mfma_f32_16x16x32_f16(ah0, br0, acc, 0, 0, 0);
            acc = __builtin_amdgcn_mfma_f32_16x16x32_f16(ah1, br1, acc, 0, 0, 0);
            acc = __builtin_amdgcn_mfma_f32_16x16x32_f16(ar0, bh0, acc, 0, 0, 0);
            acc = __builtin_amdgcn_mfma_f32_16x16x32_f16(ar1, bh1, acc, 0, 0, 0);
            sacc[jc] = acc;
        }
    }
    __syncthreads();   // chunk 0 staged; S reads done

    // ---- G tiles: K-loop over V in 8 chunks of 64, double-buffered ----
    f32x4 gacc[4] = {{0.f,0.f,0.f,0.f},{0.f,0.f,0.f,0.f},
                     {0.f,0.f,0.f,0.f},{0.f,0.f,0.f,0.f}};
    for (int c = 0; c < 8; ++c) {
        int b = c & 1;
        if (c < 7) {
            int nb = (c + 1) & 1;
            uint4* la = (uint4*)(sVa[nb]); uint4* lb = (uint4*)(sVb[nb]);
            const uint4* ga = gVa + (size_t)(c + 1) * 8;
            const uint4* gb = gVb + (size_t)(c + 1) * 8;
            for (int t = tid; t < 512; t += 256) {
                int r = t >> 3, cc = t & 7;
                la[r * 9 + cc] = ga[(size_t)r * 64 + cc];
                lb[r * 9 + cc] = gb[(size_t)r * 64 + cc];
            }
        }
        const half8 va0 = *(const half8*)(sVa[b] + (ibase + m) * 72 + quad * 8);
        const half8 va1 = *(const half8*)(sVa[b] + (ibase + m) * 72 + 32 + quad * 8);
#pragma unroll
        for (int jc = 0; jc < 4; ++jc) {
            const half8 vb0 = *(const half8*)(sVb[b] + (jc * 16 + m) * 72 + quad * 8);
            const half8 vb1 = *(const half8*)(sVb[b] + (jc * 16 + m) * 72 + 32 + quad * 8);
            gacc[jc] = __builtin_amdgcn_mfma_f32_16x16x32_f16(va0, vb0, gacc[jc], 0, 0, 0);
            gacc[jc] = __builtin_amdgcn_mfma_f32_16x16x32_f16(va1, vb1, gacc[jc], 0, 0, 0);
        }
        __syncthreads();
    }

    // ---- epilogue: select + softmax weights + per-row/col reduce ----
    float zi[4] = {0,0,0,0}, ni_[4] = {0,0,0,0};   // i-side, indexed by r
    float zj[4] = {0,0,0,0}, nj_[4] = {0,0,0,0};   // j-side, indexed by jc
#pragma unroll
    for (int jc = 0; jc < 4; ++jc) {
        int jl = jc * 16 + m, jg = j0 + jl;
        float nej = sNeJ[jl], nnj = sNJ[jl];
        f32x4 s4 = sacc[jc], g4 = gacc[jc];
#pragma unroll
        for (int r = 0; r < 4; ++r) {
            int il = ibase + quad * 4 + r, ig = i0 + il;
            float nei = sNeI[il], nni = sNI[il];
            float s = s4[r];
            bool pred = (s > fminf(nei, nej) - SEL_T) && (!diag || ig < jg);
            if (pred) {
                float wi = __expf(s - nei);
                float wj = __expf(s - nej);
                float wd = nni + nnj - 2.f * g4[r];
                zi[r] += wi;  ni_[r] += wi * wd;
                zj[jc] += wj; nj_[jc] += wj * wd;
            }
        }
    }
    // i-side: reduce over m (16 lanes), rows exclusive to this wave
#pragma unroll
    for (int msk = 1; msk < 16; msk <<= 1) {
#pragma unroll
        for (int r = 0; r < 4; ++r) {
            zi[r]  += __shfl_xor(zi[r],  msk, 64);
            ni_[r] += __shfl_xor(ni_[r], msk, 64);
        }
    }
    if (m == 0) {
#pragma unroll
        for (int r = 0; r < 4; ++r) {
            int row = i0 + ibase + quad * 4 + r;
            atomicAdd(Z + row,   zi[r]);
            atomicAdd(num + row, ni_[r]);
        }
    }
    // j-side: reduce over quad, combine waves through LDS
#pragma unroll
    for (int msk = 16; msk < 64; msk <<= 1) {
#pragma unroll
        for (int jc = 0; jc < 4; ++jc) {
            zj[jc]  += __shfl_xor(zj[jc],  msk, 64);
            nj_[jc] += __shfl_xor(nj_[jc], msk, 64);
        }
    }
    if (quad == 0) {
#pragma unroll
        for (int jc = 0; jc < 4; ++jc) {
            sJred[wave][jc * 16 + m][0] = zj[jc];
            sJred[wave][jc * 16 + m][1] = nj_[jc];
        }
    }
    __syncthreads();
    if (tid < 64) {
        float az = 0.f, an = 0.f;
#pragma unroll
        for (int w = 0; w < 4; ++w) {
            az += sJred[w][tid][0];
            an += sJred[w][tid][1];
        }
        atomicAdd(Z + j0 + tid,   az);
        atomicAdd(num + j0 + tid, an);
    }
}

// ---------------- K3: final reduction -----------------------------------
__global__ __launch_bounds__(256) void k_final(
    const float* __restrict__ Z, const float* __restrict__ num,
    float* __restrict__ out) {
    __shared__ double sd[256];
    double acc = 0.0;
    for (int i = threadIdx.x; i < B_CELLS; i += 256) {
        float z = Z[i];
        if (z > 0.f) acc += (double)num[i] / (double)z;
    }
    sd[threadIdx.x] = acc;
    __syncthreads();
    for (int s = 128; s > 0; s >>= 1) {
        if (threadIdx.x < s) sd[threadIdx.x] += sd[threadIdx.x + s];
        __syncthreads();
    }
    if (threadIdx.x == 0)
        out[0] = (float)(sd[0] / ((double)B_CELLS * (double)B_CELLS));
}

// ---------------- host launcher -----------------------------------------
extern "C" void kernel_launch(void* const* d_in, const int* in_sizes, int n_in,
                              void* d_out, int out_size, void* d_ws, size_t ws_size,
                              hipStream_t stream) {
    const float* V = (const float*)d_in[0];   // [8192, 512] f32
    const float* E = (const float*)d_in[1];   // [8192, 64]  f32
    float* out = (float*)d_out;
    char* ws = (char*)d_ws;

    // ws layout (bytes)
    float*     n_  = (float*)(ws + 0);              // 32 KB
    float*     ne  = (float*)(ws + 32768);          // 32 KB
    float*     Z   = (float*)(ws + 65536);          // 32 KB (init 1.0 in k_prep)
    float*     num = (float*)(ws + 98304);          // 32 KB (memset 0)
    _Float16*  Eh  = (_Float16*)(ws + 131072);      // 1 MB
    _Float16*  Er  = (_Float16*)(ws + 1179648);     // 1 MB
    _Float16*  Vh  = (_Float16*)(ws + 2228224);     // 8 MB

    hipMemsetAsync((void*)num, 0, 32768, stream);

    k_prep <<<2048, 256, 0, stream>>>(V, E, n_, ne, Z, Eh, Er, Vh);
    k_mega <<<16384, 256, 0, stream>>>(Eh, Er, Vh, ne, n_, Z, num);
    k_final<<<1, 256, 0, stream>>>(Z, num, out);
}